// Round 2
// baseline (1406.031 us; speedup 1.0000x reference)
//
#include <hip/hip_runtime.h>
#include <hip/hip_bf16.h>
#include <math.h>

#define N_NODES 100000
#define N_EDGES 400000
#define N_PAIRS 100000

// ---------------------------------------------------------------------------
// Generic row-blocked GEMM:
//   Y[i][rel*COUT + c] = (BIAS ? bias[c] : 0) + sum_k X[i][k] * W[rel][k][c]
// for rel in [0, NREL). W is [NREL][CIN][COUT] contiguous. Y row stride is
// NREL*COUT. Block = (COUT/VCOL)*NREL threads; each thread owns VCOL columns.
// X rows staged in LDS, broadcast-read (no bank conflicts).
// ---------------------------------------------------------------------------
template<int CIN, int COUT, int NREL, int ROWS, int VCOL, bool RELU, bool BIAS>
__global__ void gemm_kernel(const float* __restrict__ X, const float* __restrict__ W,
                            const float* __restrict__ bias, float* __restrict__ Y,
                            int nrows) {
    constexpr int CPT = COUT / VCOL;          // col-groups per relation
    constexpr int NT  = CPT * NREL;           // threads per block
    __shared__ float xs[ROWS][CIN];

    const int r0  = blockIdx.x * ROWS;
    const int t   = threadIdx.x;
    const int rel = t / CPT;
    const int ttc = t % CPT;

    for (int idx = t; idx < ROWS * CIN; idx += NT) {
        int r = idx / CIN, k = idx % CIN;
        int row = r0 + r;
        xs[r][k] = (row < nrows) ? X[(size_t)row * CIN + k] : 0.0f;
    }
    __syncthreads();

    float acc[ROWS][VCOL];
#pragma unroll
    for (int r = 0; r < ROWS; r++)
#pragma unroll
        for (int v = 0; v < VCOL; v++)
            acc[r][v] = BIAS ? bias[ttc + v * CPT] : 0.0f;

    for (int k = 0; k < CIN; k++) {
        float wv[VCOL];
#pragma unroll
        for (int v = 0; v < VCOL; v++)
            wv[v] = W[((size_t)rel * CIN + k) * COUT + ttc + v * CPT];
#pragma unroll
        for (int r = 0; r < ROWS; r++) {
            float xv = xs[r][k];
#pragma unroll
            for (int v = 0; v < VCOL; v++)
                acc[r][v] = fmaf(xv, wv[v], acc[r][v]);
        }
    }

#pragma unroll
    for (int r = 0; r < ROWS; r++) {
        int row = r0 + r;
        if (row < nrows) {
#pragma unroll
            for (int v = 0; v < VCOL; v++) {
                float val = acc[r][v];
                if (RELU) val = fmaxf(val, 0.0f);
                Y[(size_t)row * (NREL * COUT) + rel * COUT + ttc + v * CPT] = val;
            }
        }
    }
}

// ---------------------------------------------------------------------------
// Degree count + reciprocal
// ---------------------------------------------------------------------------
__global__ void deg_kernel(const int* __restrict__ dst, const int* __restrict__ etype,
                           float* __restrict__ deg) {
    int e = blockIdx.x * 256 + threadIdx.x;
    if (e < N_EDGES) atomicAdd(&deg[(size_t)etype[e] * N_NODES + dst[e]], 1.0f);
}

__global__ void inv_kernel(float* __restrict__ deg) {
    int i = blockIdx.x * 256 + threadIdx.x;
    if (i < 2 * N_NODES) deg[i] = 1.0f / fmaxf(deg[i], 1.0f);
}

// ---------------------------------------------------------------------------
// Edge scatter: Y[dst][c] += H[src-lo][etype*C + c] * inv[etype][dst]
// One thread per (edge, channel); H row stride = 2*C. Only src in [lo,hi).
// ---------------------------------------------------------------------------
template<int C, int LOGC>
__global__ void scatter_kernel(const int* __restrict__ src, const int* __restrict__ dst,
                               const int* __restrict__ etype, const float* __restrict__ H,
                               const float* __restrict__ inv, float* __restrict__ Y,
                               int lo, int hi) {
    unsigned gid = blockIdx.x * 256u + threadIdx.x;
    unsigned e = gid >> LOGC;
    if (e >= N_EDGES) return;
    int s = src[e];
    if (s < lo || s >= hi) return;
    int c = gid & (C - 1);
    int r = etype[e];
    int d = dst[e];
    float scale = inv[(size_t)r * N_NODES + d];
    float v = H[((size_t)(s - lo) * 2 + r) * C + c] * scale;
    atomicAdd(&Y[(size_t)d * C + c], v);
}

// ---------------------------------------------------------------------------
__global__ void relu_kernel(float* __restrict__ y, int n) {
    int i = blockIdx.x * 256 + threadIdx.x;
    if (i < n) y[i] = fmaxf(y[i], 0.0f);
}

// ---------------------------------------------------------------------------
// Decode: out[p] = sigmoid( z[s]·fcw[0:128] + z[d]·fcw[128:256] + fcb )
// One 64-lane wave per pair, 4 waves per block. fp32 output.
// ---------------------------------------------------------------------------
__global__ void decode_kernel(const float* __restrict__ z, const int* __restrict__ dec,
                              const float* __restrict__ fcw, const float* __restrict__ fcb,
                              float* __restrict__ out) {
    int wid  = blockIdx.x * 4 + (threadIdx.x >> 6);
    int lane = threadIdx.x & 63;
    if (wid >= N_PAIRS) return;
    int s = dec[wid];
    int d = dec[N_PAIRS + wid];
    float v = z[(size_t)s * 128 + lane]      * fcw[lane]
            + z[(size_t)s * 128 + 64 + lane] * fcw[64 + lane]
            + z[(size_t)d * 128 + lane]      * fcw[128 + lane]
            + z[(size_t)d * 128 + 64 + lane] * fcw[192 + lane];
#pragma unroll
    for (int off = 32; off > 0; off >>= 1) v += __shfl_down(v, off);
    if (lane == 0) out[wid] = 1.0f / (1.0f + expf(-(v + fcb[0])));
}

// ---------------------------------------------------------------------------
extern "C" void kernel_launch(void* const* d_in, const int* in_sizes, int n_in,
                              void* d_out, int out_size, void* d_ws, size_t ws_size,
                              hipStream_t stream) {
    const float* x0        = (const float*)d_in[0];   // [50000,128]
    const float* x1        = (const float*)d_in[1];   // [50000,64]
    const int*   edge_idx  = (const int*)  d_in[2];   // [2,400000]
    const int*   edge_type = (const int*)  d_in[3];   // [400000]
    const int*   dec_index = (const int*)  d_in[4];   // [2,100000]
    const float* lin0_w    = (const float*)d_in[5];   // [128,128]
    const float* lin0_b    = (const float*)d_in[6];   // [128]
    const float* lin1_w    = (const float*)d_in[7];   // [64,128]
    const float* lin1_b    = (const float*)d_in[8];   // [128]
    const float* conv1_w   = (const float*)d_in[9];   // [2,128,256]
    const float* conv1_root= (const float*)d_in[10];  // [128,256]
    const float* conv1_b   = (const float*)d_in[11];  // [256]
    const float* conv2_w   = (const float*)d_in[12];  // [2,256,128]
    const float* conv2_root= (const float*)d_in[13];  // [256,128]
    const float* conv2_b   = (const float*)d_in[14];  // [128]
    const float* fc_w      = (const float*)d_in[15];  // [256,1]
    const float* fc_b      = (const float*)d_in[16];  // [1]
    float* out = (float*)d_out;

    // ---- workspace layout (floats), sized to fit whatever ws_size we got ----
    // y1 : [100000,256]  activations layer1       25,600,000
    // xz : [100000,128]  x (layer1) then z (layer2) alias  12,800,000
    // deg: [2,100000]    degree -> reciprocal        200,000
    // H  : remainder     per-chunk message buffer [rows, 2*Cout]
    float* ws  = (float*)d_ws;
    float* y1  = ws;
    float* xz  = y1  + 25600000;
    float* deg = xz  + 12800000;
    float* H   = deg + 200000;
    const size_t base_floats = 38600000;           // 154.4 MB
    size_t ws_floats = ws_size / sizeof(float);
    size_t avail = (ws_floats > base_floats) ? (ws_floats - base_floats) : 0;

    // chunk rows for the message-GEMM buffer (row = 2*Cout floats)
    int chunk1 = (int)((avail / 512) & ~(size_t)7);   // layer1: 2*256 floats/row
    int chunk2 = (int)((avail / 256) & ~(size_t)7);   // layer2: 2*128 floats/row
    if (chunk1 > N_NODES) chunk1 = N_NODES;
    if (chunk2 > N_NODES) chunk2 = N_NODES;
    if (chunk1 < 8) chunk1 = 1024;  // last-resort (would mean ws_size < ~157MB)
    if (chunk2 < 8) chunk2 = 1024;

    const int* esrc = edge_idx;             // edge_index[0]
    const int* edst = edge_idx + N_EDGES;   // edge_index[1]

    // 0) zero degree counters (only memset needed; y1/z pre-filled by root GEMM)
    hipMemsetAsync(deg, 0, (size_t)2 * N_NODES * sizeof(float), stream);

    // 1) per-type input projections -> x = xz [100000,128]
    gemm_kernel<128,128,1,8,1,false,true><<<6250, 128, 0, stream>>>(
        x0, lin0_w, lin0_b, xz, 50000);
    gemm_kernel< 64,128,1,8,1,false,true><<<6250, 128, 0, stream>>>(
        x1, lin1_w, lin1_b, xz + (size_t)50000 * 128, 50000);

    // 2) degrees (shared by both layers) -> reciprocal in place
    deg_kernel<<<(N_EDGES + 255) / 256, 256, 0, stream>>>(edst, edge_type, deg);
    inv_kernel<<<(2 * N_NODES + 255) / 256, 256, 0, stream>>>(deg);

    // 3) layer 1: y1 = bias1 + x@root1, then scatter messages
    gemm_kernel<128,256,1,8,2,false,true><<<12500, 128, 0, stream>>>(
        xz, conv1_root, conv1_b, y1, N_NODES);
    for (int lo = 0; lo < N_NODES; lo += chunk1) {
        int rows = (N_NODES - lo < chunk1) ? (N_NODES - lo) : chunk1;
        gemm_kernel<128,256,2,8,4,false,false><<<(rows + 7) / 8, 128, 0, stream>>>(
            xz + (size_t)lo * 128, conv1_w, nullptr, H, rows);
        scatter_kernel<256,8><<<(N_EDGES * 256u) / 256u, 256, 0, stream>>>(
            esrc, edst, edge_type, H, deg, y1, lo, lo + rows);
    }
    relu_kernel<<<(25600000 + 255) / 256, 256, 0, stream>>>(y1, 25600000);

    // 4) layer 2: z (=xz, x is dead) = bias2 + y1@root2, then scatter
    gemm_kernel<256,128,1,8,1,false,true><<<12500, 128, 0, stream>>>(
        y1, conv2_root, conv2_b, xz, N_NODES);
    for (int lo = 0; lo < N_NODES; lo += chunk2) {
        int rows = (N_NODES - lo < chunk2) ? (N_NODES - lo) : chunk2;
        gemm_kernel<256,128,2,8,2,false,false><<<(rows + 7) / 8, 128, 0, stream>>>(
            y1 + (size_t)lo * 256, conv2_w, nullptr, H, rows);
        scatter_kernel<128,7><<<(N_EDGES * 128u) / 256u, 256, 0, stream>>>(
            esrc, edst, edge_type, H, deg, xz, lo, lo + rows);
    }

    // 5) decode head -> out [100000] fp32
    decode_kernel<<<(N_PAIRS + 3) / 4, 256, 0, stream>>>(xz, dec_index, fc_w, fc_b, out);
}

// Round 3
// 363.170 us; speedup vs baseline: 3.8715x; 3.8715x over previous
//
#include <hip/hip_runtime.h>
#include <hip/hip_bf16.h>
#include <math.h>

#define N_NODES 100000
#define N_EDGES 400000
#define N_PAIRS 100000
#define NBINS   200000   // (rel, dst) bins

typedef short short8_t __attribute__((ext_vector_type(8)));
typedef float f32x4    __attribute__((ext_vector_type(4)));

__device__ __forceinline__ ushort f2bf(float f) {
    uint u = __float_as_uint(f);
    u += 0x7fffu + ((u >> 16) & 1u);          // RNE
    return (ushort)(u >> 16);
}
__device__ __forceinline__ float bf2f(ushort b) {
    return __uint_as_float(((uint)b) << 16);
}

// ---------------------------------------------------------------------------
// Input projection (fp32 VALU, bf16 out): xout[r][t] = bias[t] + sum_k xin[r][k]W[k][t]
// ---------------------------------------------------------------------------
template<int K>
__global__ void proj_kernel(const float* __restrict__ xin, const float* __restrict__ W,
                            const float* __restrict__ bias, ushort* __restrict__ xout,
                            int nrows) {
    __shared__ float xs[8][K];
    const int r0 = blockIdx.x * 8;
    const int t  = threadIdx.x;               // 128
    for (int idx = t; idx < 8 * K; idx += 128) {
        int r = idx / K, k = idx % K;
        int row = r0 + r;
        xs[r][k] = (row < nrows) ? xin[(size_t)row * K + k] : 0.0f;
    }
    __syncthreads();
    float acc[8];
#pragma unroll
    for (int r = 0; r < 8; r++) acc[r] = bias[t];
    for (int k = 0; k < K; k++) {
        float wv = W[(size_t)k * 128 + t];
#pragma unroll
        for (int r = 0; r < 8; r++) acc[r] = fmaf(xs[r][k], wv, acc[r]);
    }
#pragma unroll
    for (int r = 0; r < 8; r++)
        if (r0 + r < nrows) xout[(size_t)(r0 + r) * 128 + t] = f2bf(acc[r]);
}

// ---------------------------------------------------------------------------
// CSR build: histogram -> exclusive scan (3 kernels) -> fill
// ---------------------------------------------------------------------------
__global__ void hist_kernel(const int* __restrict__ dst, const int* __restrict__ et,
                            int* __restrict__ cnt) {
    int e = blockIdx.x * 256 + threadIdx.x;
    if (e < N_EDGES) atomicAdd(&cnt[et[e] * N_NODES + dst[e]], 1);
}

__global__ __launch_bounds__(1024) void scan1_kernel(const int* __restrict__ cnt,
                                                     int* __restrict__ ptr,
                                                     int* __restrict__ aux) {
    __shared__ int s[1024];
    int i = blockIdx.x * 1024 + threadIdx.x;
    int v = (i < NBINS) ? cnt[i] : 0;
    s[threadIdx.x] = v;
    __syncthreads();
    for (int off = 1; off < 1024; off <<= 1) {
        int t = (threadIdx.x >= off) ? s[threadIdx.x - off] : 0;
        __syncthreads();
        s[threadIdx.x] += t;
        __syncthreads();
    }
    if (i < NBINS) ptr[i] = s[threadIdx.x] - v;          // block-exclusive
    if (threadIdx.x == 1023) aux[blockIdx.x] = s[1023];  // block total
}

__global__ void scan2_kernel(int* __restrict__ aux, int nblk) {
    __shared__ int s[256];
    int v = (threadIdx.x < nblk) ? aux[threadIdx.x] : 0;
    s[threadIdx.x] = v;
    __syncthreads();
    for (int off = 1; off < 256; off <<= 1) {
        int t = (threadIdx.x >= off) ? s[threadIdx.x - off] : 0;
        __syncthreads();
        s[threadIdx.x] += t;
        __syncthreads();
    }
    if (threadIdx.x < nblk) aux[threadIdx.x] = s[threadIdx.x] - v;  // exclusive
}

__global__ void scan3_kernel(const int* __restrict__ aux, int* __restrict__ ptr,
                             int* __restrict__ cursor) {
    int i = blockIdx.x * 256 + threadIdx.x;
    if (i < NBINS) {
        int val = ptr[i] + aux[i >> 10];
        ptr[i] = val;
        cursor[i] = val;
    }
    if (i == 0) ptr[NBINS] = N_EDGES;
}

__global__ void fill_kernel(const int* __restrict__ src, const int* __restrict__ dst,
                            const int* __restrict__ et, int* __restrict__ cursor,
                            int* __restrict__ esorted) {
    int e = blockIdx.x * 256 + threadIdx.x;
    if (e < N_EDGES) {
        int b = et[e] * N_NODES + dst[e];
        int pos = atomicAdd(&cursor[b], 1);
        esorted[pos] = src[e];
    }
}

// ---------------------------------------------------------------------------
// CSR gather-mean: agg[bin][c] = mean over src rows (bf16 in, fp32 acc, bf16 out)
// One 64-lane wave per (rel,dst) bin; 4 waves/block.
// ---------------------------------------------------------------------------
template<int C>
__global__ void gather_kernel(const int* __restrict__ ptr, const int* __restrict__ esorted,
                              const ushort* __restrict__ X, ushort* __restrict__ agg) {
    int bin = blockIdx.x * 4 + (threadIdx.x >> 6);
    if (bin >= NBINS) return;
    int lane = threadIdx.x & 63;
    int p0 = ptr[bin], p1 = ptr[bin + 1];
    constexpr int U = C / 128;                  // uints per lane
    float acc[2 * U];
#pragma unroll
    for (int u = 0; u < 2 * U; u++) acc[u] = 0.0f;
    for (int i = p0; i < p1; i++) {
        int s = esorted[i];
        const uint* row = (const uint*)(X + (size_t)s * C);
#pragma unroll
        for (int u = 0; u < U; u++) {
            uint v = row[lane + u * 64];
            acc[2 * u]     += bf2f((ushort)(v & 0xffffu));
            acc[2 * u + 1] += bf2f((ushort)(v >> 16));
        }
    }
    float inv = (p1 > p0) ? 1.0f / (float)(p1 - p0) : 1.0f;
    uint* orow = (uint*)(agg + (size_t)bin * C);
#pragma unroll
    for (int u = 0; u < U; u++) {
        uint w = (uint)f2bf(acc[2 * u] * inv) | ((uint)f2bf(acc[2 * u + 1] * inv) << 16);
        orow[lane + u * 64] = w;
    }
}

// ---------------------------------------------------------------------------
// Weight repack: Wt[n][k] (bf16, K-major rows) from root + per-rel W (fp32)
// ---------------------------------------------------------------------------
__global__ void wc1_kernel(const float* __restrict__ root, const float* __restrict__ w,
                           ushort* __restrict__ wt) {
    int i = blockIdx.x * 256 + threadIdx.x;    // 256*384
    if (i >= 256 * 384) return;
    int n = i / 384, k = i % 384;
    float v;
    if (k < 128)      v = root[(size_t)k * 256 + n];
    else              v = w[(size_t)(k - 128) * 256 + n];   // [2,128,256] contiguous
    wt[(size_t)n * 384 + k] = f2bf(v);
}
__global__ void wc2_kernel(const float* __restrict__ root, const float* __restrict__ w,
                           ushort* __restrict__ wt) {
    int i = blockIdx.x * 256 + threadIdx.x;    // 128*768
    if (i >= 128 * 768) return;
    int n = i / 768, k = i % 768;
    float v;
    if (k < 256)      v = root[(size_t)k * 128 + n];
    else              v = w[(size_t)(k - 256) * 128 + n];   // [2,256,128] contiguous
    wt[(size_t)n * 768 + k] = f2bf(v);
}

// ---------------------------------------------------------------------------
// MFMA GEMM: out[M][NT] = [x | agg0 | agg1] @ Wt^T + bias, optional ReLU.
// A virtual: k<CIN -> Ax, else Aagg (+rel offset). 128x128 tile, 4 waves,
// wave (wr,wc) owns 64x64 quadrant, 16x16x32 bf16 MFMA fragments.
// ---------------------------------------------------------------------------
template<int CIN, int KTOT, int NT, bool RELU, bool OBF16>
__global__ __launch_bounds__(256)
void mfma_gemm_kernel(const short* __restrict__ Ax, const short* __restrict__ Aagg,
                      const short* __restrict__ Wt, const float* __restrict__ bias,
                      void* __restrict__ outp) {
    __shared__ short As[128 * 32];
    __shared__ short Bs[128 * 32];
    const int t  = threadIdx.x;
    const int m0 = blockIdx.x * 128;
    const int n0 = blockIdx.y * 128;
    const int lane = t & 63, w = t >> 6;
    const int wr = w >> 1, wc = w & 1;
    const int l15 = lane & 15, l4 = lane >> 4;

    f32x4 acc[4][4];
#pragma unroll
    for (int j = 0; j < 4; j++) {
        float bv = bias[n0 + wc * 64 + j * 16 + l15];
        f32x4 tmp = {bv, bv, bv, bv};
#pragma unroll
        for (int i = 0; i < 4; i++) acc[i][j] = tmp;
    }

    constexpr int NSTEP = KTOT / 32;
    for (int ks = 0; ks < NSTEP; ks++) {
        const int kg = ks * 32;
        const int sel = kg / CIN;
        const short* base = (sel == 0) ? Ax : (Aagg + (size_t)(sel - 1) * N_NODES * CIN);
        const int kcol = kg - sel * CIN;
        __syncthreads();
#pragma unroll
        for (int c = 0; c < 2; c++) {
            int ch = t + c * 256;
            int row = ch >> 2, off = (ch & 3) * 8;
            int rg = m0 + row;
            short8_t v;
#pragma unroll
            for (int q = 0; q < 8; q++) v[q] = 0;
            if (rg < N_NODES)
                v = *(const short8_t*)(base + (size_t)rg * CIN + kcol + off);
            *(short8_t*)&As[row * 32 + off] = v;
            short8_t bv = *(const short8_t*)(Wt + (size_t)(n0 + row) * KTOT + kg + off);
            *(short8_t*)&Bs[row * 32 + off] = bv;
        }
        __syncthreads();
        short8_t af[4], bfr[4];
#pragma unroll
        for (int i = 0; i < 4; i++)
            af[i] = *(short8_t*)&As[(wr * 64 + i * 16 + l15) * 32 + l4 * 8];
#pragma unroll
        for (int j = 0; j < 4; j++)
            bfr[j] = *(short8_t*)&Bs[(wc * 64 + j * 16 + l15) * 32 + l4 * 8];
#pragma unroll
        for (int i = 0; i < 4; i++)
#pragma unroll
            for (int j = 0; j < 4; j++)
                acc[i][j] = __builtin_amdgcn_mfma_f32_16x16x32_bf16(af[i], bfr[j], acc[i][j], 0, 0, 0);
    }

#pragma unroll
    for (int i = 0; i < 4; i++) {
#pragma unroll
        for (int r = 0; r < 4; r++) {
            int row = m0 + wr * 64 + i * 16 + l4 * 4 + r;
            if (row < N_NODES) {
#pragma unroll
                for (int j = 0; j < 4; j++) {
                    int col = n0 + wc * 64 + j * 16 + l15;
                    float v = acc[i][j][r];
                    if (RELU) v = fmaxf(v, 0.0f);
                    if (OBF16) ((ushort*)outp)[(size_t)row * NT + col] = f2bf(v);
                    else       ((float*)outp)[(size_t)row * NT + col] = v;
                }
            }
        }
    }
}

// ---------------------------------------------------------------------------
// Decode: out[p] = sigmoid( z[s]·fcw[0:128] + z[d]·fcw[128:256] + fcb )
// ---------------------------------------------------------------------------
__global__ void decode_kernel(const float* __restrict__ z, const int* __restrict__ dec,
                              const float* __restrict__ fcw, const float* __restrict__ fcb,
                              float* __restrict__ out) {
    int wid  = blockIdx.x * 4 + (threadIdx.x >> 6);
    int lane = threadIdx.x & 63;
    if (wid >= N_PAIRS) return;
    int s = dec[wid];
    int d = dec[N_PAIRS + wid];
    float v = z[(size_t)s * 128 + lane]      * fcw[lane]
            + z[(size_t)s * 128 + 64 + lane] * fcw[64 + lane]
            + z[(size_t)d * 128 + lane]      * fcw[128 + lane]
            + z[(size_t)d * 128 + 64 + lane] * fcw[192 + lane];
#pragma unroll
    for (int off = 32; off > 0; off >>= 1) v += __shfl_down(v, off);
    if (lane == 0) out[wid] = 1.0f / (1.0f + expf(-(v + fcb[0])));
}

// ---------------------------------------------------------------------------
extern "C" void kernel_launch(void* const* d_in, const int* in_sizes, int n_in,
                              void* d_out, int out_size, void* d_ws, size_t ws_size,
                              hipStream_t stream) {
    const float* x0        = (const float*)d_in[0];
    const float* x1        = (const float*)d_in[1];
    const int*   edge_idx  = (const int*)  d_in[2];
    const int*   edge_type = (const int*)  d_in[3];
    const int*   dec_index = (const int*)  d_in[4];
    const float* lin0_w    = (const float*)d_in[5];
    const float* lin0_b    = (const float*)d_in[6];
    const float* lin1_w    = (const float*)d_in[7];
    const float* lin1_b    = (const float*)d_in[8];
    const float* conv1_w   = (const float*)d_in[9];
    const float* conv1_root= (const float*)d_in[10];
    const float* conv1_b   = (const float*)d_in[11];
    const float* conv2_w   = (const float*)d_in[12];
    const float* conv2_root= (const float*)d_in[13];
    const float* conv2_b   = (const float*)d_in[14];
    const float* fc_w      = (const float*)d_in[15];
    const float* fc_b      = (const float*)d_in[16];
    float* out = (float*)d_out;

    // ---- workspace layout (bytes), ~209.2 MB total; agg2 aliases x_bf+agg1 ----
    char* W = (char*)d_ws;
    ushort* y1_bf = (ushort*)(W + 0);            //  51,200,000 B [100k][256] bf16
    ushort* x_bf  = (ushort*)(W + 51200000);     //  25,600,000 B [100k][128] bf16
    ushort* agg1  = (ushort*)(W + 76800000);     //  51,200,000 B [2*100k][128] bf16
    ushort* agg2  = (ushort*)(W + 51200000);     // 102,400,000 B [2*100k][256] bf16 (alias)
    float*  z     = (float*) (W + 153600000);    //  51,200,000 B [100k][128] fp32
    int*    cnt   = (int*)   (W + 204800000);    //     800,000 B
    int*    ptrb  = (int*)   (W + 205600000);    //     800,016 B (200001 ints)
    int*    cursor= (int*)   (W + 206400016);    //     800,000 B
    int*    aux   = (int*)   (W + 207200016);    //       4,096 B
    int*    esort = (int*)   (W + 207204112);    //   1,600,000 B
    ushort* wc1   = (ushort*)(W + 208804112);    //     196,608 B [256][384] bf16
    ushort* wc2   = (ushort*)(W + 209000720);    //     196,608 B [128][768] bf16

    const int* esrc = edge_idx;
    const int* edst = edge_idx + N_EDGES;

    // 0) zero histogram
    hipMemsetAsync(cnt, 0, (size_t)NBINS * sizeof(int), stream);

    // 1) weight repack (bf16, K-major)
    wc1_kernel<<<(256 * 384 + 255) / 256, 256, 0, stream>>>(conv1_root, conv1_w, wc1);
    wc2_kernel<<<(128 * 768 + 255) / 256, 256, 0, stream>>>(conv2_root, conv2_w, wc2);

    // 2) input projections -> x_bf
    proj_kernel<128><<<6250, 128, 0, stream>>>(x0, lin0_w, lin0_b, x_bf, 50000);
    proj_kernel< 64><<<6250, 128, 0, stream>>>(x1, lin1_w, lin1_b,
                                               x_bf + (size_t)50000 * 128, 50000);

    // 3) CSR build over (rel,dst)
    hist_kernel<<<(N_EDGES + 255) / 256, 256, 0, stream>>>(edst, edge_type, cnt);
    scan1_kernel<<<(NBINS + 1023) / 1024, 1024, 0, stream>>>(cnt, ptrb, aux);
    scan2_kernel<<<1, 256, 0, stream>>>(aux, (NBINS + 1023) / 1024);
    scan3_kernel<<<(NBINS + 255) / 256, 256, 0, stream>>>(aux, ptrb, cursor);
    fill_kernel<<<(N_EDGES + 255) / 256, 256, 0, stream>>>(esrc, edst, edge_type,
                                                           cursor, esort);

    // 4) layer 1: gather-mean + fused MFMA GEMM (+ReLU) -> y1_bf
    gather_kernel<128><<<(NBINS + 3) / 4, 256, 0, stream>>>(ptrb, esort, x_bf, agg1);
    mfma_gemm_kernel<128, 384, 256, true, true>
        <<<dim3(782, 2), 256, 0, stream>>>((const short*)x_bf, (const short*)agg1,
                                           (const short*)wc1, conv1_b, y1_bf);

    // 5) layer 2: gather-mean + fused MFMA GEMM -> z (fp32)
    gather_kernel<256><<<(NBINS + 3) / 4, 256, 0, stream>>>(ptrb, esort, y1_bf, agg2);
    mfma_gemm_kernel<256, 768, 128, false, false>
        <<<dim3(782, 1), 256, 0, stream>>>((const short*)y1_bf, (const short*)agg2,
                                           (const short*)wc2, conv2_b, z);

    // 6) decode
    decode_kernel<<<(N_PAIRS + 3) / 4, 256, 0, stream>>>(z, dec_index, fc_w, fc_b, out);
}

// Round 4
// 350.481 us; speedup vs baseline: 4.0117x; 1.0362x over previous
//
#include <hip/hip_runtime.h>
#include <hip/hip_bf16.h>
#include <math.h>

#define N_NODES 100000
#define N_EDGES 400000
#define N_PAIRS 100000
#define NBINS   200000   // (rel, dst) bins

typedef short short8_t __attribute__((ext_vector_type(8)));
typedef float f32x4    __attribute__((ext_vector_type(4)));

__device__ __forceinline__ ushort f2bf(float f) {
    uint u = __float_as_uint(f);
    u += 0x7fffu + ((u >> 16) & 1u);          // RNE
    return (ushort)(u >> 16);
}
__device__ __forceinline__ float bf2f(ushort b) {
    return __uint_as_float(((uint)b) << 16);
}
__device__ __forceinline__ uint packbf(float a, float b) {
    return (uint)f2bf(a) | ((uint)f2bf(b) << 16);
}

#define GLDS16(gp, lp) \
    __builtin_amdgcn_global_load_lds((const __attribute__((address_space(1))) uint*)(gp), \
                                     (__attribute__((address_space(3))) uint*)(lp), 16, 0, 0)

// ---------------------------------------------------------------------------
// Input projection (fp32 VALU, bf16 out into A1 x-slab, row stride 384)
// ---------------------------------------------------------------------------
template<int K>
__global__ void proj_kernel(const float* __restrict__ xin, const float* __restrict__ W,
                            const float* __restrict__ bias, ushort* __restrict__ xout,
                            int nrows) {
    __shared__ float xs[8][K];
    const int r0 = blockIdx.x * 8;
    const int t  = threadIdx.x;               // 128
    for (int idx = t; idx < 8 * K; idx += 128) {
        int r = idx / K, k = idx % K;
        int row = r0 + r;
        xs[r][k] = (row < nrows) ? xin[(size_t)row * K + k] : 0.0f;
    }
    __syncthreads();
    float acc[8];
#pragma unroll
    for (int r = 0; r < 8; r++) acc[r] = bias[t];
    for (int k = 0; k < K; k++) {
        float wv = W[(size_t)k * 128 + t];
#pragma unroll
        for (int r = 0; r < 8; r++) acc[r] = fmaf(xs[r][k], wv, acc[r]);
    }
#pragma unroll
    for (int r = 0; r < 8; r++)
        if (r0 + r < nrows) xout[(size_t)(r0 + r) * 384 + t] = f2bf(acc[r]);
}

// ---------------------------------------------------------------------------
// CSR build: histogram -> exclusive scan (3 kernels) -> fill
// ---------------------------------------------------------------------------
__global__ void hist_kernel(const int* __restrict__ dst, const int* __restrict__ et,
                            int* __restrict__ cnt) {
    int e = blockIdx.x * 256 + threadIdx.x;
    if (e < N_EDGES) atomicAdd(&cnt[et[e] * N_NODES + dst[e]], 1);
}

__global__ __launch_bounds__(1024) void scan1_kernel(const int* __restrict__ cnt,
                                                     int* __restrict__ ptr,
                                                     int* __restrict__ aux) {
    __shared__ int s[1024];
    int i = blockIdx.x * 1024 + threadIdx.x;
    int v = (i < NBINS) ? cnt[i] : 0;
    s[threadIdx.x] = v;
    __syncthreads();
    for (int off = 1; off < 1024; off <<= 1) {
        int t = (threadIdx.x >= off) ? s[threadIdx.x - off] : 0;
        __syncthreads();
        s[threadIdx.x] += t;
        __syncthreads();
    }
    if (i < NBINS) ptr[i] = s[threadIdx.x] - v;          // block-exclusive
    if (threadIdx.x == 1023) aux[blockIdx.x] = s[1023];  // block total
}

__global__ void scan2_kernel(int* __restrict__ aux, int nblk) {
    __shared__ int s[256];
    int v = (threadIdx.x < nblk) ? aux[threadIdx.x] : 0;
    s[threadIdx.x] = v;
    __syncthreads();
    for (int off = 1; off < 256; off <<= 1) {
        int t = (threadIdx.x >= off) ? s[threadIdx.x - off] : 0;
        __syncthreads();
        s[threadIdx.x] += t;
        __syncthreads();
    }
    if (threadIdx.x < nblk) aux[threadIdx.x] = s[threadIdx.x] - v;  // exclusive
}

__global__ void scan3_kernel(const int* __restrict__ aux, int* __restrict__ ptr,
                             int* __restrict__ cursor) {
    int i = blockIdx.x * 256 + threadIdx.x;
    if (i < NBINS) {
        int val = ptr[i] + aux[i >> 10];
        ptr[i] = val;
        cursor[i] = val;
    }
    if (i == 0) ptr[NBINS] = N_EDGES;
}

__global__ void fill_kernel(const int* __restrict__ src, const int* __restrict__ dst,
                            const int* __restrict__ et, int* __restrict__ cursor,
                            int* __restrict__ esorted) {
    int e = blockIdx.x * 256 + threadIdx.x;
    if (e < N_EDGES) {
        int b = et[e] * N_NODES + dst[e];
        int pos = atomicAdd(&cursor[b], 1);
        esorted[pos] = src[e];
    }
}

// ---------------------------------------------------------------------------
// Layer-1 gather-mean: one wave per dst node, both relations (2x MLP).
// Reads A1 x-slab (cols 0:128), writes agg slabs (cols 128:256, 256:384).
// ---------------------------------------------------------------------------
__global__ void gather1_kernel(const int* __restrict__ ptr, const int* __restrict__ es,
                               ushort* __restrict__ A1) {
    int d = blockIdx.x * 4 + (threadIdx.x >> 6);
    if (d >= N_NODES) return;
    int lane = threadIdx.x & 63;
    int p0 = ptr[d],           p1 = ptr[d + 1];
    int q0 = ptr[N_NODES + d], q1 = ptr[N_NODES + d + 1];
    int n0 = p1 - p0, n1 = q1 - q0;
    int n  = n0 > n1 ? n0 : n1;
    float a0 = 0, a1 = 0, b0 = 0, b1 = 0;
    for (int k = 0; k < n; k++) {
        if (k < n0) {
            int s = es[p0 + k];
            uint v = *(const uint*)(A1 + (size_t)s * 384 + lane * 2);
            a0 += bf2f((ushort)(v & 0xffffu)); a1 += bf2f((ushort)(v >> 16));
        }
        if (k < n1) {
            int s = es[q0 + k];
            uint v = *(const uint*)(A1 + (size_t)s * 384 + lane * 2);
            b0 += bf2f((ushort)(v & 0xffffu)); b1 += bf2f((ushort)(v >> 16));
        }
    }
    float i0 = n0 ? 1.0f / (float)n0 : 0.0f;
    float i1 = n1 ? 1.0f / (float)n1 : 0.0f;
    uint* row = (uint*)(A1 + (size_t)d * 384);
    row[64  + lane] = packbf(a0 * i0, a1 * i0);
    row[128 + lane] = packbf(b0 * i1, b1 * i1);
}

// ---------------------------------------------------------------------------
// Layer-2 combine: z[d] = H[d][0:128] + mean_r0 H[s][128:256] + mean_r1 H[s][256:384]
// One wave per dst node. z fp32.
// ---------------------------------------------------------------------------
__global__ void combine2_kernel(const int* __restrict__ ptr, const int* __restrict__ es,
                                const ushort* __restrict__ H, float* __restrict__ z) {
    int d = blockIdx.x * 4 + (threadIdx.x >> 6);
    if (d >= N_NODES) return;
    int lane = threadIdx.x & 63;
    int p0 = ptr[d],           p1 = ptr[d + 1];
    int q0 = ptr[N_NODES + d], q1 = ptr[N_NODES + d + 1];
    int n0 = p1 - p0, n1 = q1 - q0;
    int n  = n0 > n1 ? n0 : n1;
    uint rv = *(const uint*)(H + (size_t)d * 384 + lane * 2);
    float r0 = bf2f((ushort)(rv & 0xffffu)), r1 = bf2f((ushort)(rv >> 16));
    float a0 = 0, a1 = 0, b0 = 0, b1 = 0;
    for (int k = 0; k < n; k++) {
        if (k < n0) {
            int s = es[p0 + k];
            uint v = *(const uint*)(H + (size_t)s * 384 + 128 + lane * 2);
            a0 += bf2f((ushort)(v & 0xffffu)); a1 += bf2f((ushort)(v >> 16));
        }
        if (k < n1) {
            int s = es[q0 + k];
            uint v = *(const uint*)(H + (size_t)s * 384 + 256 + lane * 2);
            b0 += bf2f((ushort)(v & 0xffffu)); b1 += bf2f((ushort)(v >> 16));
        }
    }
    float i0 = n0 ? 1.0f / (float)n0 : 0.0f;
    float i1 = n1 ? 1.0f / (float)n1 : 0.0f;
    float2 o;
    o.x = r0 + a0 * i0 + b0 * i1;
    o.y = r1 + a1 * i0 + b1 * i1;
    *(float2*)(z + (size_t)d * 128 + lane * 2) = o;
}

// ---------------------------------------------------------------------------
// Weight repacks (bf16, K-major rows Wt[n][k])
// ---------------------------------------------------------------------------
__global__ void wc1_kernel(const float* __restrict__ root, const float* __restrict__ w,
                           ushort* __restrict__ wt) {
    int i = blockIdx.x * 256 + threadIdx.x;    // 256*384
    if (i >= 256 * 384) return;
    int n = i / 384, k = i % 384;
    float v;
    if (k < 128) v = root[(size_t)k * 256 + n];
    else         v = w[(size_t)(k - 128) * 256 + n];   // [2,128,256] contiguous
    wt[(size_t)n * 384 + k] = f2bf(v);
}
// wt2[n][k]: n<128 -> root2[k][n]; n in [128,256) -> W0[k][n-128]; n>=256 -> W1[k][n-256]
__global__ void wc2_kernel(const float* __restrict__ root, const float* __restrict__ w,
                           ushort* __restrict__ wt) {
    int i = blockIdx.x * 256 + threadIdx.x;    // 384*256
    if (i >= 384 * 256) return;
    int n = i / 256, k = i % 256;
    float v;
    if (n < 128) v = root[(size_t)k * 128 + n];
    else         v = w[((size_t)((n >> 7) - 1) * 256 + k) * 128 + (n & 127)];
    wt[(size_t)n * 256 + k] = f2bf(v);
}

// ---------------------------------------------------------------------------
// MFMA GEMM: out[M][NT] = A[M][KTOT] @ Wt^T + bias(cols < BIASN), opt ReLU.
// 128x128 tile, 4 waves (2x2 quadrants), 16x16x32 bf16 MFMA,
// global_load_lds width-16 staging (m97 structure).
// ---------------------------------------------------------------------------
template<int KTOT, int NT, int BIASN, bool RELU>
__global__ __launch_bounds__(256)
void mfma_gemm_kernel(const ushort* __restrict__ A, const ushort* __restrict__ Wt,
                      const float* __restrict__ bias, ushort* __restrict__ outp) {
    __shared__ short As[128 * 32];
    __shared__ short Bs[128 * 32];
    const int t  = threadIdx.x;
    const int m0 = blockIdx.x * 128;
    const int n0 = blockIdx.y * 128;
    const int lane = t & 63, w = t >> 6;
    const int wr = w >> 1, wc = w & 1;
    const int l15 = lane & 15, l4 = lane >> 4;

    f32x4 acc[4][4];
#pragma unroll
    for (int j = 0; j < 4; j++) {
        int col = n0 + wc * 64 + j * 16 + l15;
        float bv = (col < BIASN) ? bias[col] : 0.0f;
        f32x4 tmp = {bv, bv, bv, bv};
#pragma unroll
        for (int i = 0; i < 4; i++) acc[i][j] = tmp;
    }

    constexpr int NSTEP = KTOT / 32;
    for (int ks = 0; ks < NSTEP; ks++) {
        const int kg = ks * 32;
        __syncthreads();                       // frags of prev step consumed
#pragma unroll
        for (int c = 0; c < 2; c++) {
            int ch  = t + c * 256;             // 512 chunks of 16B per buffer
            int row = ch >> 2, off = (ch & 3) * 8;
            int rg  = m0 + row;
            if (rg > N_NODES - 1) rg = N_NODES - 1;   // clamp (extra rows discarded)
            GLDS16(A  + (size_t)rg * KTOT + kg + off,          &As[ch * 8]);
            GLDS16(Wt + (size_t)(n0 + row) * KTOT + kg + off,  &Bs[ch * 8]);
        }
        __syncthreads();                       // vmcnt(0) drained by compiler
        short8_t af[4], bfr[4];
#pragma unroll
        for (int i = 0; i < 4; i++)
            af[i] = *(short8_t*)&As[(wr * 64 + i * 16 + l15) * 32 + l4 * 8];
#pragma unroll
        for (int j = 0; j < 4; j++)
            bfr[j] = *(short8_t*)&Bs[(wc * 64 + j * 16 + l15) * 32 + l4 * 8];
#pragma unroll
        for (int i = 0; i < 4; i++)
#pragma unroll
            for (int j = 0; j < 4; j++)
                acc[i][j] = __builtin_amdgcn_mfma_f32_16x16x32_bf16(af[i], bfr[j], acc[i][j], 0, 0, 0);
    }

#pragma unroll
    for (int i = 0; i < 4; i++) {
#pragma unroll
        for (int r = 0; r < 4; r++) {
            int row = m0 + wr * 64 + i * 16 + l4 * 4 + r;
            if (row < N_NODES) {
#pragma unroll
                for (int j = 0; j < 4; j++) {
                    int col = n0 + wc * 64 + j * 16 + l15;
                    float v = acc[i][j][r];
                    if (RELU) v = fmaxf(v, 0.0f);
                    outp[(size_t)row * NT + col] = f2bf(v);
                }
            }
        }
    }
}

// ---------------------------------------------------------------------------
// Decode: out[p] = sigmoid( z[s]·fcw[0:128] + z[d]·fcw[128:256] + fcb )
// ---------------------------------------------------------------------------
__global__ void decode_kernel(const float* __restrict__ z, const int* __restrict__ dec,
                              const float* __restrict__ fcw, const float* __restrict__ fcb,
                              float* __restrict__ out) {
    int wid  = blockIdx.x * 4 + (threadIdx.x >> 6);
    int lane = threadIdx.x & 63;
    if (wid >= N_PAIRS) return;
    int s = dec[wid];
    int d = dec[N_PAIRS + wid];
    float v = z[(size_t)s * 128 + lane]      * fcw[lane]
            + z[(size_t)s * 128 + 64 + lane] * fcw[64 + lane]
            + z[(size_t)d * 128 + lane]      * fcw[128 + lane]
            + z[(size_t)d * 128 + 64 + lane] * fcw[192 + lane];
#pragma unroll
    for (int off = 32; off > 0; off >>= 1) v += __shfl_down(v, off);
    if (lane == 0) out[wid] = 1.0f / (1.0f + expf(-(v + fcb[0])));
}

// ---------------------------------------------------------------------------
extern "C" void kernel_launch(void* const* d_in, const int* in_sizes, int n_in,
                              void* d_out, int out_size, void* d_ws, size_t ws_size,
                              hipStream_t stream) {
    const float* x0        = (const float*)d_in[0];
    const float* x1        = (const float*)d_in[1];
    const int*   edge_idx  = (const int*)  d_in[2];
    const int*   edge_type = (const int*)  d_in[3];
    const int*   dec_index = (const int*)  d_in[4];
    const float* lin0_w    = (const float*)d_in[5];
    const float* lin0_b    = (const float*)d_in[6];
    const float* lin1_w    = (const float*)d_in[7];
    const float* lin1_b    = (const float*)d_in[8];
    const float* conv1_w   = (const float*)d_in[9];
    const float* conv1_root= (const float*)d_in[10];
    const float* conv1_b   = (const float*)d_in[11];
    const float* conv2_w   = (const float*)d_in[12];
    const float* conv2_root= (const float*)d_in[13];
    const float* conv2_b   = (const float*)d_in[14];
    const float* fc_w      = (const float*)d_in[15];
    const float* fc_b      = (const float*)d_in[16];
    float* out = (float*)d_out;

    // ---- workspace layout (bytes), ~132.4 MB; H aliases A1, z aliases y1 ----
    char* W = (char*)d_ws;
    ushort* A1    = (ushort*)(W + 0);            // 76,800,000 B [100k][384] bf16 = [x|agg0|agg1]
    ushort* H     = (ushort*)(W + 0);            // alias: [100k][384] bf16 (A1 dead after gemm1)
    ushort* y1    = (ushort*)(W + 76800000);     // 51,200,000 B [100k][256] bf16
    float*  z     = (float*) (W + 76800000);     // alias: [100k][128] f32 (y1 dead after gemm2)
    int*    cnt   = (int*)   (W + 128000000);    //    800,000 B
    int*    ptrb  = (int*)   (W + 128800000);    //    800,016 B (200001 ints)
    int*    cursor= (int*)   (W + 129600016);    //    800,000 B
    int*    aux   = (int*)   (W + 130400016);    //      4,096 B
    int*    esort = (int*)   (W + 130404112);    //  1,600,000 B
    ushort* wc1   = (ushort*)(W + 132004112);    //    196,608 B [256][384] bf16
    ushort* wc2   = (ushort*)(W + 132200720);    //    196,608 B [384][256] bf16

    const int* esrc = edge_idx;
    const int* edst = edge_idx + N_EDGES;

    // 0) zero histogram
    hipMemsetAsync(cnt, 0, (size_t)NBINS * sizeof(int), stream);

    // 1) weight repacks
    wc1_kernel<<<(256 * 384 + 255) / 256, 256, 0, stream>>>(conv1_root, conv1_w, wc1);
    wc2_kernel<<<(384 * 256 + 255) / 256, 256, 0, stream>>>(conv2_root, conv2_w, wc2);

    // 2) input projections -> A1 x-slab (cols 0:128, stride 384)
    proj_kernel<128><<<6250, 128, 0, stream>>>(x0, lin0_w, lin0_b, A1, 50000);
    proj_kernel< 64><<<6250, 128, 0, stream>>>(x1, lin1_w, lin1_b,
                                               A1 + (size_t)50000 * 384, 50000);

    // 3) CSR build over (rel,dst)
    hist_kernel<<<(N_EDGES + 255) / 256, 256, 0, stream>>>(edst, edge_type, cnt);
    scan1_kernel<<<(NBINS + 1023) / 1024, 1024, 0, stream>>>(cnt, ptrb, aux);
    scan2_kernel<<<1, 256, 0, stream>>>(aux, (NBINS + 1023) / 1024);
    scan3_kernel<<<(NBINS + 255) / 256, 256, 0, stream>>>(aux, ptrb, cursor);
    fill_kernel<<<(N_EDGES + 255) / 256, 256, 0, stream>>>(esrc, edst, edge_type,
                                                           cursor, esort);

    // 4) layer 1: per-dst gather-mean into A1 agg slabs, then fused GEMM+ReLU -> y1
    gather1_kernel<<<(N_NODES + 3) / 4, 256, 0, stream>>>(ptrb, esort, A1);
    mfma_gemm_kernel<384, 256, 256, true>
        <<<dim3(782, 2), 256, 0, stream>>>(A1, wc1, conv1_b, y1);

    // 5) layer 2: GEMM y1 @ [root2|W0|W1] -> H (aliases A1), then combine -> z
    mfma_gemm_kernel<256, 384, 128, false>
        <<<dim3(782, 3), 256, 0, stream>>>(y1, wc2, conv2_b, H);
    combine2_kernel<<<(N_NODES + 3) / 4, 256, 0, stream>>>(ptrb, esort, H, z);

    // 6) decode
    decode_kernel<<<(N_PAIRS + 3) / 4, 256, 0, stream>>>(z, dec_index, fc_w, fc_b, out);
}

// Round 5
// 282.774 us; speedup vs baseline: 4.9723x; 1.2394x over previous
//
#include <hip/hip_runtime.h>
#include <hip/hip_bf16.h>
#include <math.h>

#define N_NODES 100000
#define N_EDGES 400000
#define N_PAIRS 100000
#define NBINS   200000   // (rel, dst) bins

typedef short short8_t __attribute__((ext_vector_type(8)));
typedef float f32x4    __attribute__((ext_vector_type(4)));

__device__ __forceinline__ ushort f2bf(float f) {
    uint u = __float_as_uint(f);
    u += 0x7fffu + ((u >> 16) & 1u);          // RNE
    return (ushort)(u >> 16);
}
__device__ __forceinline__ float bf2f(ushort b) {
    return __uint_as_float(((uint)b) << 16);
}
__device__ __forceinline__ uint packbf(float a, float b) {
    return (uint)f2bf(a) | ((uint)f2bf(b) << 16);
}

#define GLDS16(gp, lp) \
    __builtin_amdgcn_global_load_lds((const __attribute__((address_space(1))) uint*)(gp), \
                                     (__attribute__((address_space(3))) uint*)(lp), 16, 0, 0)

// ---------------------------------------------------------------------------
// fp32 -> bf16 cast (vectorized, grid-stride)
// ---------------------------------------------------------------------------
__global__ void cast_kernel(const float* __restrict__ in, ushort* __restrict__ outp, int n4) {
    int i = blockIdx.x * 256 + threadIdx.x;
    int stride = gridDim.x * 256;
    for (; i < n4; i += stride) {
        float4 v = ((const float4*)in)[i];
        ushort4 o;
        o.x = f2bf(v.x); o.y = f2bf(v.y); o.z = f2bf(v.z); o.w = f2bf(v.w);
        ((ushort4*)outp)[i] = o;
    }
}

// ---------------------------------------------------------------------------
// Weight repacks (bf16, K-major rows Wt[n][k])
// ---------------------------------------------------------------------------
__global__ void wlin_kernel(const float* __restrict__ w, ushort* __restrict__ wt, int K) {
    int i = blockIdx.x * 256 + threadIdx.x;    // 128*K
    if (i >= 128 * K) return;
    int n = i / K, k = i - n * K;
    wt[i] = f2bf(w[(size_t)k * 128 + n]);
}
__global__ void wc1_kernel(const float* __restrict__ root, const float* __restrict__ w,
                           ushort* __restrict__ wt) {
    int i = blockIdx.x * 256 + threadIdx.x;    // 256*384
    if (i >= 256 * 384) return;
    int n = i / 384, k = i % 384;
    float v;
    if (k < 128) v = root[(size_t)k * 256 + n];
    else         v = w[(size_t)(k - 128) * 256 + n];   // [2,128,256] contiguous
    wt[(size_t)n * 384 + k] = f2bf(v);
}
__global__ void wc2_kernel(const float* __restrict__ root, const float* __restrict__ w,
                           ushort* __restrict__ wt) {
    int i = blockIdx.x * 256 + threadIdx.x;    // 384*256
    if (i >= 384 * 256) return;
    int n = i / 256, k = i % 256;
    float v;
    if (n < 128) v = root[(size_t)k * 128 + n];
    else         v = w[((size_t)((n >> 7) - 1) * 256 + k) * 128 + (n & 127)];
    wt[(size_t)n * 256 + k] = f2bf(v);
}

// ---------------------------------------------------------------------------
// CSR build: histogram -> exclusive scan (3 kernels) -> fill
// ---------------------------------------------------------------------------
__global__ void hist_kernel(const int* __restrict__ dst, const int* __restrict__ et,
                            int* __restrict__ cnt) {
    int e = blockIdx.x * 256 + threadIdx.x;
    if (e < N_EDGES) atomicAdd(&cnt[et[e] * N_NODES + dst[e]], 1);
}

__global__ __launch_bounds__(1024) void scan1_kernel(const int* __restrict__ cnt,
                                                     int* __restrict__ ptr,
                                                     int* __restrict__ aux) {
    __shared__ int s[1024];
    int i = blockIdx.x * 1024 + threadIdx.x;
    int v = (i < NBINS) ? cnt[i] : 0;
    s[threadIdx.x] = v;
    __syncthreads();
    for (int off = 1; off < 1024; off <<= 1) {
        int t = (threadIdx.x >= off) ? s[threadIdx.x - off] : 0;
        __syncthreads();
        s[threadIdx.x] += t;
        __syncthreads();
    }
    if (i < NBINS) ptr[i] = s[threadIdx.x] - v;          // block-exclusive
    if (threadIdx.x == 1023) aux[blockIdx.x] = s[1023];  // block total
}

__global__ void scan2_kernel(int* __restrict__ aux, int nblk) {
    __shared__ int s[256];
    int v = (threadIdx.x < nblk) ? aux[threadIdx.x] : 0;
    s[threadIdx.x] = v;
    __syncthreads();
    for (int off = 1; off < 256; off <<= 1) {
        int t = (threadIdx.x >= off) ? s[threadIdx.x - off] : 0;
        __syncthreads();
        s[threadIdx.x] += t;
        __syncthreads();
    }
    if (threadIdx.x < nblk) aux[threadIdx.x] = s[threadIdx.x] - v;  // exclusive
}

__global__ void scan3_kernel(const int* __restrict__ aux, int* __restrict__ ptr,
                             int* __restrict__ cursor) {
    int i = blockIdx.x * 256 + threadIdx.x;
    if (i < NBINS) {
        int val = ptr[i] + aux[i >> 10];
        ptr[i] = val;
        cursor[i] = val;
    }
    if (i == 0) ptr[NBINS] = N_EDGES;
}

__global__ void fill_kernel(const int* __restrict__ src, const int* __restrict__ dst,
                            const int* __restrict__ et, int* __restrict__ cursor,
                            int* __restrict__ esorted) {
    int e = blockIdx.x * 256 + threadIdx.x;
    if (e < N_EDGES) {
        int b = et[e] * N_NODES + dst[e];
        int pos = atomicAdd(&cursor[b], 1);
        esorted[pos] = src[e];
    }
}

// ---------------------------------------------------------------------------
// Layer-1 gather-mean: one wave per dst node, both relations, unroll-2
// (up to 4 independent row loads in flight). Branch conditions are
// wave-uniform (d, n0, n1 uniform per wave) -> scalar branches.
// ---------------------------------------------------------------------------
__global__ void gather1_kernel(const int* __restrict__ ptr, const int* __restrict__ es,
                               ushort* __restrict__ A1) {
    int d = blockIdx.x * 4 + (threadIdx.x >> 6);
    if (d >= N_NODES) return;
    int lane = threadIdx.x & 63;
    int p0 = ptr[d],           p1 = ptr[d + 1];
    int q0 = ptr[N_NODES + d], q1 = ptr[N_NODES + d + 1];
    int n0 = p1 - p0, n1 = q1 - q0;
    int n  = n0 > n1 ? n0 : n1;
    float a0 = 0, a1 = 0, b0 = 0, b1 = 0;
    for (int k = 0; k < n; k += 2) {
        uint v00 = 0, v01 = 0, v10 = 0, v11 = 0;
        if (k < n0)     v00 = *(const uint*)(A1 + (size_t)es[p0 + k] * 384 + lane * 2);
        if (k + 1 < n0) v01 = *(const uint*)(A1 + (size_t)es[p0 + k + 1] * 384 + lane * 2);
        if (k < n1)     v10 = *(const uint*)(A1 + (size_t)es[q0 + k] * 384 + lane * 2);
        if (k + 1 < n1) v11 = *(const uint*)(A1 + (size_t)es[q0 + k + 1] * 384 + lane * 2);
        a0 += bf2f((ushort)(v00 & 0xffffu)) + bf2f((ushort)(v01 & 0xffffu));
        a1 += bf2f((ushort)(v00 >> 16))     + bf2f((ushort)(v01 >> 16));
        b0 += bf2f((ushort)(v10 & 0xffffu)) + bf2f((ushort)(v11 & 0xffffu));
        b1 += bf2f((ushort)(v10 >> 16))     + bf2f((ushort)(v11 >> 16));
    }
    float i0 = n0 ? 1.0f / (float)n0 : 0.0f;
    float i1 = n1 ? 1.0f / (float)n1 : 0.0f;
    uint* row = (uint*)(A1 + (size_t)d * 384);
    row[64  + lane] = packbf(a0 * i0, a1 * i0);
    row[128 + lane] = packbf(b0 * i1, b1 * i1);
}

// ---------------------------------------------------------------------------
// Layer-2 combine: z[d] = H[d][0:128] + mean_r0 H[s][128:256] + mean_r1 H[s][256:384]
// One wave per dst node, unroll-2. z output bf16.
// ---------------------------------------------------------------------------
__global__ void combine2_kernel(const int* __restrict__ ptr, const int* __restrict__ es,
                                const ushort* __restrict__ H, ushort* __restrict__ zb) {
    int d = blockIdx.x * 4 + (threadIdx.x >> 6);
    if (d >= N_NODES) return;
    int lane = threadIdx.x & 63;
    int p0 = ptr[d],           p1 = ptr[d + 1];
    int q0 = ptr[N_NODES + d], q1 = ptr[N_NODES + d + 1];
    int n0 = p1 - p0, n1 = q1 - q0;
    int n  = n0 > n1 ? n0 : n1;
    uint rv = *(const uint*)(H + (size_t)d * 384 + lane * 2);
    float r0 = bf2f((ushort)(rv & 0xffffu)), r1 = bf2f((ushort)(rv >> 16));
    float a0 = 0, a1 = 0, b0 = 0, b1 = 0;
    for (int k = 0; k < n; k += 2) {
        uint v00 = 0, v01 = 0, v10 = 0, v11 = 0;
        if (k < n0)     v00 = *(const uint*)(H + (size_t)es[p0 + k] * 384 + 128 + lane * 2);
        if (k + 1 < n0) v01 = *(const uint*)(H + (size_t)es[p0 + k + 1] * 384 + 128 + lane * 2);
        if (k < n1)     v10 = *(const uint*)(H + (size_t)es[q0 + k] * 384 + 256 + lane * 2);
        if (k + 1 < n1) v11 = *(const uint*)(H + (size_t)es[q0 + k + 1] * 384 + 256 + lane * 2);
        a0 += bf2f((ushort)(v00 & 0xffffu)) + bf2f((ushort)(v01 & 0xffffu));
        a1 += bf2f((ushort)(v00 >> 16))     + bf2f((ushort)(v01 >> 16));
        b0 += bf2f((ushort)(v10 & 0xffffu)) + bf2f((ushort)(v11 & 0xffffu));
        b1 += bf2f((ushort)(v10 >> 16))     + bf2f((ushort)(v11 >> 16));
    }
    float i0 = n0 ? 1.0f / (float)n0 : 0.0f;
    float i1 = n1 ? 1.0f / (float)n1 : 0.0f;
    uint* orow = (uint*)(zb + (size_t)d * 128);
    orow[lane] = packbf(r0 + a0 * i0 + b0 * i1, r1 + a1 * i0 + b1 * i1);
}

// ---------------------------------------------------------------------------
// 2-phase double-buffered MFMA GEMM: out[row][n0+col] = A[row][:]@Wt[col][:]
// + bias(col<BIASN), opt ReLU. 128x128 tile, 4 waves, 16x16x32 bf16 MFMA.
// global_load_lds width-16 staging; next K-step staged during current compute
// with counted s_waitcnt vmcnt(4) (never 0 mid-loop).
// ---------------------------------------------------------------------------
template<int KTOT, int OST, int BIASN, bool RELU>
__global__ __launch_bounds__(256)
void mfma_gemm_kernel(const ushort* __restrict__ A, const ushort* __restrict__ Wt,
                      const float* __restrict__ bias, ushort* __restrict__ outp,
                      int nrows) {
    __shared__ short As[2][128 * 32];
    __shared__ short Bs[2][128 * 32];
    const int t  = threadIdx.x;
    const int m0 = blockIdx.x * 128;
    const int n0 = blockIdx.y * 128;
    const int lane = t & 63, w = t >> 6;
    const int wr = w >> 1, wc = w & 1;
    const int l15 = lane & 15, l4 = lane >> 4;

    // staging addresses: thread t covers LDS chunks t and t+256 (rows row0, row0+64)
    const int row0 = t >> 2, off0 = (t & 3) * 8;
    int rg0 = m0 + row0;      if (rg0 >= nrows) rg0 = nrows - 1;
    int rg1 = m0 + row0 + 64; if (rg1 >= nrows) rg1 = nrows - 1;
    const ushort* a0p = A + (size_t)rg0 * KTOT + off0;
    const ushort* a1p = A + (size_t)rg1 * KTOT + off0;
    const ushort* b0p = Wt + (size_t)(n0 + row0) * KTOT + off0;
    const ushort* b1p = Wt + (size_t)(n0 + row0 + 64) * KTOT + off0;

#define STAGE(b, kg) do { \
        GLDS16(a0p + (kg), &As[b][t * 8]); \
        GLDS16(a1p + (kg), &As[b][(t + 256) * 8]); \
        GLDS16(b0p + (kg), &Bs[b][t * 8]); \
        GLDS16(b1p + (kg), &Bs[b][(t + 256) * 8]); \
    } while (0)

    f32x4 acc[4][4];
#pragma unroll
    for (int j = 0; j < 4; j++) {
        int col = n0 + wc * 64 + j * 16 + l15;
        float bv = (col < BIASN) ? bias[col] : 0.0f;
        f32x4 tmp = {bv, bv, bv, bv};
#pragma unroll
        for (int i = 0; i < 4; i++) acc[i][j] = tmp;
    }

    STAGE(0, 0);
    constexpr int NSTEP = KTOT / 32;
    for (int ks = 0; ks < NSTEP; ks++) {
        const int b = ks & 1;
        if (ks + 1 < NSTEP) {
            STAGE(b ^ 1, (ks + 1) * 32);
            asm volatile("s_waitcnt vmcnt(4)" ::: "memory");   // current buf done, next in flight
        } else {
            asm volatile("s_waitcnt vmcnt(0)" ::: "memory");
        }
        asm volatile("s_barrier" ::: "memory");                // buf b staged for all waves
        short8_t af[4], bfr[4];
#pragma unroll
        for (int i = 0; i < 4; i++)
            af[i] = *(short8_t*)&As[b][(wr * 64 + i * 16 + l15) * 32 + l4 * 8];
#pragma unroll
        for (int j = 0; j < 4; j++)
            bfr[j] = *(short8_t*)&Bs[b][(wc * 64 + j * 16 + l15) * 32 + l4 * 8];
#pragma unroll
        for (int i = 0; i < 4; i++)
#pragma unroll
            for (int j = 0; j < 4; j++)
                acc[i][j] = __builtin_amdgcn_mfma_f32_16x16x32_bf16(af[i], bfr[j], acc[i][j], 0, 0, 0);
        asm volatile("s_barrier" ::: "memory");                // reads done before re-stage
    }
#undef STAGE

#pragma unroll
    for (int i = 0; i < 4; i++) {
#pragma unroll
        for (int r = 0; r < 4; r++) {
            int row = m0 + wr * 64 + i * 16 + l4 * 4 + r;
            if (row < nrows) {
#pragma unroll
                for (int j = 0; j < 4; j++) {
                    int col = n0 + wc * 64 + j * 16 + l15;
                    float v = acc[i][j][r];
                    if (RELU) v = fmaxf(v, 0.0f);
                    outp[(size_t)row * OST + col] = f2bf(v);
                }
            }
        }
    }
}

// ---------------------------------------------------------------------------
// Decode: out[p] = sigmoid( z[s]·fcw[0:128] + z[d]·fcw[128:256] + fcb ), z bf16
// ---------------------------------------------------------------------------
__global__ void decode_kernel(const ushort* __restrict__ zb, const int* __restrict__ dec,
                              const float* __restrict__ fcw, const float* __restrict__ fcb,
                              float* __restrict__ out) {
    int wid  = blockIdx.x * 4 + (threadIdx.x >> 6);
    int lane = threadIdx.x & 63;
    if (wid >= N_PAIRS) return;
    int s = dec[wid];
    int d = dec[N_PAIRS + wid];
    uint vs = ((const uint*)(zb + (size_t)s * 128))[lane];
    uint vd = ((const uint*)(zb + (size_t)d * 128))[lane];
    float v = bf2f((ushort)(vs & 0xffffu)) * fcw[2 * lane]
            + bf2f((ushort)(vs >> 16))     * fcw[2 * lane + 1]
            + bf2f((ushort)(vd & 0xffffu)) * fcw[128 + 2 * lane]
            + bf2f((ushort)(vd >> 16))     * fcw[128 + 2 * lane + 1];
#pragma unroll
    for (int off = 32; off > 0; off >>= 1) v += __shfl_down(v, off);
    if (lane == 0) out[wid] = 1.0f / (1.0f + expf(-(v + fcb[0])));
}

// ---------------------------------------------------------------------------
extern "C" void kernel_launch(void* const* d_in, const int* in_sizes, int n_in,
                              void* d_out, int out_size, void* d_ws, size_t ws_size,
                              hipStream_t stream) {
    const float* x0        = (const float*)d_in[0];
    const float* x1        = (const float*)d_in[1];
    const int*   edge_idx  = (const int*)  d_in[2];
    const int*   edge_type = (const int*)  d_in[3];
    const int*   dec_index = (const int*)  d_in[4];
    const float* lin0_w    = (const float*)d_in[5];
    const float* lin0_b    = (const float*)d_in[6];
    const float* lin1_w    = (const float*)d_in[7];
    const float* lin1_b    = (const float*)d_in[8];
    const float* conv1_w   = (const float*)d_in[9];
    const float* conv1_root= (const float*)d_in[10];
    const float* conv1_b   = (const float*)d_in[11];
    const float* conv2_w   = (const float*)d_in[12];
    const float* conv2_root= (const float*)d_in[13];
    const float* conv2_b   = (const float*)d_in[14];
    const float* fc_w      = (const float*)d_in[15];
    const float* fc_b      = (const float*)d_in[16];
    float* out = (float*)d_out;

    // ---- workspace layout (bytes), ~151.6 MB; H aliases A1, zb aliases y1 ----
    char* W = (char*)d_ws;
    ushort* A1    = (ushort*)(W + 0);            // 76,800,000 B [100k][384] = [x|agg0|agg1]
    ushort* H     = (ushort*)(W + 0);            // alias (A1 dead after gemm1)
    ushort* y1    = (ushort*)(W + 76800000);     // 51,200,000 B [100k][256]
    ushort* zb    = (ushort*)(W + 76800000);     // alias: [100k][128] bf16 (y1 dead after gemm2)
    int*    cnt   = (int*)   (W + 128000000);
    int*    ptrb  = (int*)   (W + 128800000);
    int*    cursor= (int*)   (W + 129600016);
    int*    aux   = (int*)   (W + 130400016);
    int*    esort = (int*)   (W + 130404112);
    ushort* wc1   = (ushort*)(W + 132004112);    // [256][384] bf16
    ushort* wc2   = (ushort*)(W + 132200720);    // [384][256] bf16
    ushort* wl0   = (ushort*)(W + 132397328);    // [128][128] bf16
    ushort* wl1   = (ushort*)(W + 132430096);    // [128][64]  bf16
    ushort* x0bf  = (ushort*)(W + 132446480);    // [50000][128] bf16
    ushort* x1bf  = (ushort*)(W + 145246480);    // [50000][64]  bf16

    const int* esrc = edge_idx;
    const int* edst = edge_idx + N_EDGES;

    // 0) zero histogram
    hipMemsetAsync(cnt, 0, (size_t)NBINS * sizeof(int), stream);

    // 1) casts + weight repacks
    cast_kernel<<<2048, 256, 0, stream>>>(x0, x0bf, 50000 * 128 / 4);
    cast_kernel<<<2048, 256, 0, stream>>>(x1, x1bf, 50000 * 64 / 4);
    wlin_kernel<<<64, 256, 0, stream>>>(lin0_w, wl0, 128);
    wlin_kernel<<<32, 256, 0, stream>>>(lin1_w, wl1, 64);
    wc1_kernel<<<(256 * 384 + 255) / 256, 256, 0, stream>>>(conv1_root, conv1_w, wc1);
    wc2_kernel<<<(384 * 256 + 255) / 256, 256, 0, stream>>>(conv2_root, conv2_w, wc2);

    // 2) CSR build over (rel,dst)
    hist_kernel<<<(N_EDGES + 255) / 256, 256, 0, stream>>>(edst, edge_type, cnt);
    scan1_kernel<<<(NBINS + 1023) / 1024, 1024, 0, stream>>>(cnt, ptrb, aux);
    scan2_kernel<<<1, 256, 0, stream>>>(aux, (NBINS + 1023) / 1024);
    scan3_kernel<<<(NBINS + 255) / 256, 256, 0, stream>>>(aux, ptrb, cursor);
    fill_kernel<<<(N_EDGES + 255) / 256, 256, 0, stream>>>(esrc, edst, edge_type,
                                                           cursor, esort);

    // 3) input projections via MFMA -> A1 x-slab (cols 0:128, stride 384)
    mfma_gemm_kernel<128, 384, 128, false>
        <<<dim3(391, 1), 256, 0, stream>>>(x0bf, wl0, lin0_b, A1, 50000);
    mfma_gemm_kernel<64, 384, 128, false>
        <<<dim3(391, 1), 256, 0, stream>>>(x1bf, wl1, lin1_b,
                                           A1 + (size_t)50000 * 384, 50000);

    // 4) layer 1: per-dst gather-mean into A1 agg slabs, then fused GEMM+ReLU -> y1
    gather1_kernel<<<(N_NODES + 3) / 4, 256, 0, stream>>>(ptrb, esort, A1);
    mfma_gemm_kernel<384, 256, 256, true>
        <<<dim3(782, 2), 256, 0, stream>>>(A1, wc1, conv1_b, y1, N_NODES);

    // 5) layer 2: GEMM y1 @ [root2|W0|W1] -> H (aliases A1), then combine -> zb (bf16)
    mfma_gemm_kernel<256, 384, 128, false>
        <<<dim3(782, 3), 256, 0, stream>>>(y1, wc2, conv2_b, H, N_NODES);
    combine2_kernel<<<(N_NODES + 3) / 4, 256, 0, stream>>>(ptrb, esort, H, zb);

    // 6) decode
    decode_kernel<<<(N_PAIRS + 3) / 4, 256, 0, stream>>>(zb, dec_index, fc_w, fc_b, out);
}